// Round 4
// baseline (116.844 us; speedup 1.0000x reference)
//
#include <hip/hip_runtime.h>

// Entangle layer — real-part-only output (verified PASS in R3):
// input  re,im: (B=128, Q=8, R=64, A=2, K=64) float32, 8,388,608 elems each
// output: (B, Q, 2R=128, A=2, K=64) float32 = Re(reference), 16,777,216 elems
//   X branch:  out[b,q,r0, 1-a, k] = c * re,            c = 2^-0.25
//   Z branch:  out[b,q,64+r0, a, k] = sgn * p * (re-im), p = 2^-0.75,
//              sgn = +1 (a=0), -1 (a=1)
// Streaming kernel: 134 MB mandatory traffic -> ~21 us floor @ 6.3 TB/s.
// R3 evidence: kernel absent from top-5 dispatches (< 41.7 us); reported
// dur_us ~112 us matches harness poison/restore arithmetic, not the kernel.
// This round: nontemporal loads/stores (no reuse on input or output).

typedef float v4f __attribute__((ext_vector_type(4)));

__global__ __launch_bounds__(256) void entangle_kernel(
    const v4f* __restrict__ re, const v4f* __restrict__ im,
    v4f* __restrict__ out, int n, int nout4) {
  int tid = blockIdx.x * blockDim.x + threadIdx.x;
  if (tid >= n) return;

  constexpr float c = 0.84089641525371454303f;  // 2^-0.25
  constexpr float p = 0.59460355750136053336f;  // 2^-0.75

  v4f vr = __builtin_nontemporal_load(re + tid);
  v4f vi = __builtin_nontemporal_load(im + tid);

  // tid -> (bq, r0, a, k4); 16 float4 per K=64 row
  int k4    = tid & 15;
  int rest  = tid >> 4;
  int a     = rest & 1;
  int rest2 = rest >> 1;
  int r0    = rest2 & 63;
  int bq    = rest2 >> 6;      // b*8 + q, 0..1023

  // X branch: out[bq, r0, 1-a, k4] = c * re
  int xo = (((bq << 7) + r0) * 2 + (1 - a)) * 16 + k4;
  if (xo < nout4) {
    __builtin_nontemporal_store(c * vr, out + xo);
  }

  // Z branch: out[bq, 64+r0, a, k4] = sgn*p*(re - im)
  float s = a ? -p : p;
  int zo = (((bq << 7) + 64 + r0) * 2 + a) * 16 + k4;
  if (zo < nout4) {
    __builtin_nontemporal_store(s * (vr - vi), out + zo);
  }
}

extern "C" void kernel_launch(void* const* d_in, const int* in_sizes, int n_in,
                              void* d_out, int out_size, void* d_ws, size_t ws_size,
                              hipStream_t stream) {
  const v4f* re = (const v4f*)d_in[0];
  const v4f* im = (const v4f*)d_in[1];
  v4f* out = (v4f*)d_out;

  int n = in_sizes[0] / 4;        // 2,097,152 threads
  int nout4 = out_size / 4;       // 4,194,304 float4 slots
  int block = 256;
  int grid = (n + block - 1) / block;  // 8192
  entangle_kernel<<<grid, block, 0, stream>>>(re, im, out, n, nout4);
}